// Round 1
// baseline (1079.290 us; speedup 1.0000x reference)
//
#include <hip/hip_runtime.h>
#include <hip/hip_bf16.h>
#include <stdint.h>

typedef __bf16 bf16;
typedef __bf16 bf16x8 __attribute__((ext_vector_type(8)));
typedef float f32x4 __attribute__((ext_vector_type(4)));
typedef unsigned short u16t;
typedef unsigned int u32t;

#define MFMA16(a, b, c) __builtin_amdgcn_mfma_f32_16x16x32_bf16((a), (b), (c), 0, 0, 0)

typedef const void __attribute__((address_space(1))) cg_void;
typedef void __attribute__((address_space(3))) lds_void;
#define GLL16(g, l) __builtin_amdgcn_global_load_lds((cg_void*)(g), (lds_void*)(l), 16, 0, 0)

// ---------------- ws layout (bytes) ----------------
// flag | biasQKV f32[1536] | biasProj f32[512] | wqkvT bf16[1536][512] |
// wprojT bf16[512][512] | qkv bf16[131072][1536] | attn bf16[131072][512]
#define OFF_FLAG   0
#define OFF_BQKV   256
#define OFF_BPROJ  6400
#define OFF_WQKVT  8448
#define OFF_WPROJT 1581312
#define OFF_QKV    2105600
#define OFF_ATTN   404758784
// total = 538,976,512 bytes

// chunk-swizzled LDS tile: tile is 128 rows x 32 cols bf16 = 512 chunks of 16B.
// logical (row r, col8 c) -> physical chunk (r<<2) | (c ^ swizzle(r)).
// Gives 2-way-max bank aliasing for both ds_read_b128 frag reads and staging.
__device__ __forceinline__ int swz(int r, int c) {
    return (r << 2) | (c ^ (r & 3) ^ ((r >> 2) & 3));
}

// ---------------- dtype detector ----------------
// bf16 buffer: every halfword has exponent field in a sane range for N(0,1)-ish data.
// f32 buffer: even halfwords are low mantissa bits -> uniform -> ~14% pass rate.
__global__ __launch_bounds__(256) void k_detect(const u16t* x, u32t* flag) {
    __shared__ int cnt;
    if (threadIdx.x == 0) cnt = 0;
    __syncthreads();
    u16t h = x[threadIdx.x * 2];
    int e = (h >> 7) & 0xFF;
    int ok = (h == 0) || (e >= 100 && e <= 134);
    atomicAdd(&cnt, ok);
    __syncthreads();
    if (threadIdx.x == 0) flag[0] = (cnt >= 200) ? 1u : 0u;
}

// ---------------- weight prep: transpose to [N][K] bf16, biases -> f32 ----------------
__global__ __launch_bounds__(256) void k_prep(const void* w_qkv, const void* b_qkv,
                                              const void* w_proj, const void* b_proj,
                                              const u32t* flagp, char* ws) {
    bf16* wqkvT = (bf16*)(ws + OFF_WQKVT);
    bf16* wprojT = (bf16*)(ws + OFF_WPROJT);
    float* bq = (float*)(ws + OFF_BQKV);
    float* bp = (float*)(ws + OFF_BPROJ);
    const int isbf = (int)flagp[0];
    long long gid = (long long)blockIdx.x * 256 + threadIdx.x;
    if (gid < 786432) {            // wqkvT[n][k] = w_qkv[k][n], n<1536, k<512
        int o = (int)gid;
        int n = o >> 9, k = o & 511;
        float v = isbf ? (float)((const bf16*)w_qkv)[k * 1536 + n]
                       : ((const float*)w_qkv)[k * 1536 + n];
        wqkvT[o] = (bf16)v;
    } else if (gid < 786432 + 262144) {   // wprojT[n][k] = w_proj[k][n], n<512, k<512
        int o = (int)(gid - 786432);
        int n = o >> 9, k = o & 511;
        float v = isbf ? (float)((const bf16*)w_proj)[k * 512 + n]
                       : ((const float*)w_proj)[k * 512 + n];
        wprojT[o] = (bf16)v;
    } else {
        int o = (int)(gid - 786432 - 262144);
        if (o < 1536)
            bq[o] = isbf ? (float)((const bf16*)b_qkv)[o] : ((const float*)b_qkv)[o];
        else {
            int o2 = o - 1536;
            bp[o2] = isbf ? (float)((const bf16*)b_proj)[o2] : ((const float*)b_proj)[o2];
        }
    }
}

// ---------------- GEMM: C[M][NTOT] = A[M][512] * Bt[NTOT][512]^T + bias ----------------
// 128x128 tile, BK=32, 256 threads (4 waves, each 64x64), global_load_lds staging.
// amode: 0 = A always bf16; 1 = A dtype by flag (f32 when flag==0)
// omode: 1 = out always bf16; 2 = out dtype by flag
template <int NTOT>
__global__ __launch_bounds__(256) void k_gemm(const void* Ax, const bf16* Bt,
                                              const float* bias, void* Cp,
                                              const u32t* flagp, int amode, int omode) {
    __shared__ __align__(16) u16t As[4096];
    __shared__ __align__(16) u16t Bs[4096];
    const int isbf = (int)flagp[0];
    const int a_is_f32 = (amode == 1) && !isbf;
    const int out_bf16 = (omode == 1) || isbf;

    const int t = threadIdx.x;
    const int w = t >> 6, lane = t & 63;
    const int ln = lane & 15, qd = lane >> 4;
    const int m0 = blockIdx.y * 128;
    const int n0 = blockIdx.x * 128;
    const int wr = (w >> 1) * 64, wc = (w & 1) * 64;

    // staging: thread t owns physical chunks t and t+256 of each tile
    const int p0 = t, p1 = t + 256;
    const int r0 = p0 >> 2, c0 = (p0 & 3) ^ (r0 & 3) ^ ((r0 >> 2) & 3);
    const int r1 = p1 >> 2, c1 = (p1 & 3) ^ (r1 & 3) ^ ((r1 >> 2) & 3);
    const bf16* Ab = (const bf16*)Ax;
    const float* Af = (const float*)Ax;
    size_t aoff0 = (size_t)(m0 + r0) * 512 + c0 * 8;
    size_t aoff1 = (size_t)(m0 + r1) * 512 + c1 * 8;
    size_t boff0 = (size_t)(n0 + r0) * 512 + c0 * 8;
    size_t boff1 = (size_t)(n0 + r1) * 512 + c1 * 8;
    u16t* ldsA0 = &As[(w * 64) * 8];
    u16t* ldsA1 = &As[(256 + w * 64) * 8];
    u16t* ldsB0 = &Bs[(w * 64) * 8];
    u16t* ldsB1 = &Bs[(256 + w * 64) * 8];

    // fragment LDS element offsets (loop-invariant)
    int aoffs[4], boffs[4];
#pragma unroll
    for (int i = 0; i < 4; ++i) {
        aoffs[i] = swz(wr + i * 16 + ln, qd) * 8;
        boffs[i] = swz(wc + i * 16 + ln, qd) * 8;
    }

    f32x4 acc[4][4];
    f32x4 zero = {0.f, 0.f, 0.f, 0.f};
#pragma unroll
    for (int i = 0; i < 4; ++i)
#pragma unroll
        for (int j = 0; j < 4; ++j) acc[i][j] = zero;

    for (int kt = 0; kt < 16; ++kt) {
        if (a_is_f32) {
            float4 v0 = *(const float4*)(Af + aoff0);
            float4 v1 = *(const float4*)(Af + aoff0 + 4);
            bf16x8 h0;
            h0[0] = (bf16)v0.x; h0[1] = (bf16)v0.y; h0[2] = (bf16)v0.z; h0[3] = (bf16)v0.w;
            h0[4] = (bf16)v1.x; h0[5] = (bf16)v1.y; h0[6] = (bf16)v1.z; h0[7] = (bf16)v1.w;
            *(bf16x8*)(void*)&As[p0 * 8] = h0;
            float4 v2 = *(const float4*)(Af + aoff1);
            float4 v3 = *(const float4*)(Af + aoff1 + 4);
            bf16x8 h1;
            h1[0] = (bf16)v2.x; h1[1] = (bf16)v2.y; h1[2] = (bf16)v2.z; h1[3] = (bf16)v2.w;
            h1[4] = (bf16)v3.x; h1[5] = (bf16)v3.y; h1[6] = (bf16)v3.z; h1[7] = (bf16)v3.w;
            *(bf16x8*)(void*)&As[p1 * 8] = h1;
        } else {
            GLL16(Ab + aoff0, ldsA0);
            GLL16(Ab + aoff1, ldsA1);
        }
        GLL16(Bt + boff0, ldsB0);
        GLL16(Bt + boff1, ldsB1);
        __syncthreads();
        bf16x8 af[4], bfr[4];
#pragma unroll
        for (int i = 0; i < 4; ++i) af[i] = *(const bf16x8*)(void*)&As[aoffs[i]];
#pragma unroll
        for (int j = 0; j < 4; ++j) bfr[j] = *(const bf16x8*)(void*)&Bs[boffs[j]];
#pragma unroll
        for (int i = 0; i < 4; ++i)
#pragma unroll
            for (int j = 0; j < 4; ++j) acc[i][j] = MFMA16(af[i], bfr[j], acc[i][j]);
        __syncthreads();
        aoff0 += 32; aoff1 += 32; boff0 += 32; boff1 += 32;
    }

    float bj[4];
#pragma unroll
    for (int j = 0; j < 4; ++j) bj[j] = bias[n0 + wc + j * 16 + ln];

    if (out_bf16) {
        bf16* C = (bf16*)Cp;
#pragma unroll
        for (int i = 0; i < 4; ++i)
#pragma unroll
            for (int j = 0; j < 4; ++j)
#pragma unroll
                for (int rr = 0; rr < 4; ++rr) {
                    size_t row = (size_t)m0 + wr + i * 16 + qd * 4 + rr;
                    int col = n0 + wc + j * 16 + ln;
                    C[row * NTOT + col] = (bf16)(acc[i][j][rr] + bj[j]);
                }
    } else {
        float* C = (float*)Cp;
#pragma unroll
        for (int i = 0; i < 4; ++i)
#pragma unroll
            for (int j = 0; j < 4; ++j)
#pragma unroll
                for (int rr = 0; rr < 4; ++rr) {
                    size_t row = (size_t)m0 + wr + i * 16 + qd * 4 + rr;
                    int col = n0 + wc + j * 16 + ln;
                    C[row * NTOT + col] = acc[i][j][rr] + bj[j];
                }
    }
}

// ---------------- fused gaussian-window attention: one wave per (b,h) ----------------
__global__ __launch_bounds__(256) void k_attn(const bf16* qkv, bf16* attn) {
    __shared__ __align__(16) bf16 P[4][64 * 72];   // per-wave P matrix, padded stride 72
    const int t = threadIdx.x;
    const int w = t >> 6, lane = t & 63;
    const int ln = lane & 15, qd = lane >> 4, q8 = qd * 8;
    const int bh = blockIdx.x * 4 + w;
    const int b = bh >> 4, h = bh & 15;
    const size_t rowbase = (size_t)b * 64 * 1536;
    const int colq = h * 32 + q8;

    // Q and K fragments straight from global (each load = 16 rows x 64B lines)
    bf16x8 aq[4], bk[4];
#pragma unroll
    for (int i = 0; i < 4; ++i)
        aq[i] = *(const bf16x8*)(qkv + rowbase + (size_t)(i * 16 + ln) * 1536 + colq);
#pragma unroll
    for (int j = 0; j < 4; ++j)
        bk[j] = *(const bf16x8*)(qkv + rowbase + (size_t)(j * 16 + ln) * 1536 + 512 + colq);

    f32x4 zero = {0.f, 0.f, 0.f, 0.f};
    f32x4 s[4][4];
#pragma unroll
    for (int i = 0; i < 4; ++i)
#pragma unroll
        for (int j = 0; j < 4; ++j) s[i][j] = MFMA16(aq[i], bk[j], zero);

    // Gaussian mask, separable: Ks[n][m] = e(|dy|) e(|dx|) / (S1(yn) S1(xn))
    const float INV2S2 = 3.28731097961867f;   // 1/(2*0.39^2)
    {
        int c = lane & 7;
        float S1 = 0.f;
#pragma unroll
        for (int c2 = 0; c2 < 8; ++c2) {
            int d = c - c2;
            S1 += __expf(-(float)(d * d) * INV2S2);
        }
        float invS1 = 1.0f / S1;
        const int ymb = ln >> 3, xm = ln & 7, yq = qd >> 1, xq = (qd & 1) * 4;
        float FY[4][4], FX[4];
#pragma unroll
        for (int i = 0; i < 4; ++i) {
            int yn = 2 * i + yq;
            float g = __shfl(invS1, yn, 64);
#pragma unroll
            for (int j = 0; j < 4; ++j) {
                int dy = yn - (2 * j + ymb);
                FY[i][j] = __expf(-(float)(dy * dy) * INV2S2) * g;
            }
        }
#pragma unroll
        for (int rr = 0; rr < 4; ++rr) {
            int xn = xq + rr;
            int dx = xn - xm;
            FX[rr] = __expf(-(float)(dx * dx) * INV2S2) * __shfl(invS1, xn, 64);
        }

        const float SCALE = 0.17677669529663687f;  // 1/sqrt(32)
        // softmax over keys m: per (i,rr) row, reduce over j (in-lane) x 16 lanes (quad group)
#pragma unroll
        for (int i = 0; i < 4; ++i)
#pragma unroll
            for (int rr = 0; rr < 4; ++rr) {
                float lj[4];
                float mx = -1e30f;
#pragma unroll
                for (int j = 0; j < 4; ++j) {
                    lj[j] = s[i][j][rr] * SCALE * FY[i][j] * FX[rr];
                    mx = fmaxf(mx, lj[j]);
                }
                mx = fmaxf(mx, __shfl_xor(mx, 1));
                mx = fmaxf(mx, __shfl_xor(mx, 2));
                mx = fmaxf(mx, __shfl_xor(mx, 4));
                mx = fmaxf(mx, __shfl_xor(mx, 8));
                float sum = 0.f;
#pragma unroll
                for (int j = 0; j < 4; ++j) {
                    lj[j] = __expf(lj[j] - mx);
                    sum += lj[j];
                }
                sum += __shfl_xor(sum, 1);
                sum += __shfl_xor(sum, 2);
                sum += __shfl_xor(sum, 4);
                sum += __shfl_xor(sum, 8);
                float inv = 1.0f / sum;
                int n = i * 16 + qd * 4 + rr;
#pragma unroll
                for (int j = 0; j < 4; ++j)
                    P[w][n * 72 + j * 16 + ln] = (bf16)(lj[j] * inv);
            }
    }

    // O = P * V  (P via LDS round-trip into A-layout; V gathered as B fragments)
    f32x4 o[4][2];
#pragma unroll
    for (int i = 0; i < 4; ++i) {
        o[i][0] = zero;
        o[i][1] = zero;
    }
#pragma unroll
    for (int kc = 0; kc < 64; kc += 32) {
        bf16x8 bv[2];
#pragma unroll
        for (int j2 = 0; j2 < 2; ++j2)
#pragma unroll
            for (int jj = 0; jj < 8; ++jj)
                bv[j2][jj] = qkv[rowbase + (size_t)(kc + q8 + jj) * 1536 + 1024 + h * 32 + j2 * 16 + ln];
#pragma unroll
        for (int i = 0; i < 4; ++i) {
            bf16x8 ap = *(const bf16x8*)(void*)&P[w][(i * 16 + ln) * 72 + kc + q8];
#pragma unroll
            for (int j2 = 0; j2 < 2; ++j2) o[i][j2] = MFMA16(ap, bv[j2], o[i][j2]);
        }
    }
#pragma unroll
    for (int i = 0; i < 4; ++i)
#pragma unroll
        for (int j2 = 0; j2 < 2; ++j2)
#pragma unroll
            for (int rr = 0; rr < 4; ++rr)
                attn[((size_t)b * 64 + i * 16 + qd * 4 + rr) * 512 + h * 32 + j2 * 16 + ln] =
                    (bf16)(o[i][j2][rr]);
}

extern "C" void kernel_launch(void* const* d_in, const int* in_sizes, int n_in,
                              void* d_out, int out_size, void* d_ws, size_t ws_size,
                              hipStream_t stream) {
    const void* x = d_in[0];
    const void* w_qkv = d_in[1];
    const void* b_qkv = d_in[2];
    const void* w_proj = d_in[3];
    const void* b_proj = d_in[4];
    char* ws = (char*)d_ws;
    u32t* flag = (u32t*)(ws + OFF_FLAG);
    bf16* wqkvT = (bf16*)(ws + OFF_WQKVT);
    bf16* wprojT = (bf16*)(ws + OFF_WPROJT);
    float* bq = (float*)(ws + OFF_BQKV);
    float* bp = (float*)(ws + OFF_BPROJ);
    bf16* qkv = (bf16*)(ws + OFF_QKV);
    bf16* attn = (bf16*)(ws + OFF_ATTN);

    k_detect<<<1, 256, 0, stream>>>((const u16t*)x, flag);
    k_prep<<<4104, 256, 0, stream>>>(w_qkv, b_qkv, w_proj, b_proj, flag, ws);
    // QKV GEMM: [131072,512] @ [512,1536] -> qkv bf16
    k_gemm<1536><<<dim3(12, 1024), 256, 0, stream>>>(x, wqkvT, bq, qkv, flag, 1, 1);
    // attention: one wave per (b,h)
    k_attn<<<8192, 256, 0, stream>>>(qkv, attn);
    // proj GEMM: [131072,512] @ [512,512] -> d_out (dtype per flag)
    k_gemm<512><<<dim3(4, 1024), 256, 0, stream>>>(attn, wprojT, bp, d_out, flag, 0, 2);
}

// Round 2
// 941.270 us; speedup vs baseline: 1.1466x; 1.1466x over previous
//
#include <hip/hip_runtime.h>
#include <hip/hip_bf16.h>
#include <stdint.h>

typedef __bf16 bf16;
typedef __bf16 bf16x8 __attribute__((ext_vector_type(8)));
typedef float f32x4 __attribute__((ext_vector_type(4)));
typedef unsigned short u16t;
typedef unsigned int u32t;

#define MFMA16(a, b, c) __builtin_amdgcn_mfma_f32_16x16x32_bf16((a), (b), (c), 0, 0, 0)

typedef const void __attribute__((address_space(1))) cg_void;
typedef void __attribute__((address_space(3))) lds_void;
#define GLL16(g, l) __builtin_amdgcn_global_load_lds((cg_void*)(g), (lds_void*)(l), 16, 0, 0)

// ---------------- ws layout (bytes) ----------------
#define OFF_FLAG   0
#define OFF_BQKV   256
#define OFF_BPROJ  6400
#define OFF_WQKVT  8448
#define OFF_WPROJT 1581312
#define OFF_QKV    2105600
#define OFF_ATTN   404758784
// total = 538,976,512 bytes

// ---------------- dtype detector ----------------
__global__ __launch_bounds__(256) void k_detect(const u16t* x, u32t* flag) {
    __shared__ int cnt;
    if (threadIdx.x == 0) cnt = 0;
    __syncthreads();
    u16t h = x[threadIdx.x * 2];
    int e = (h >> 7) & 0xFF;
    int ok = (h == 0) || (e >= 100 && e <= 134);
    atomicAdd(&cnt, ok);
    __syncthreads();
    if (threadIdx.x == 0) flag[0] = (cnt >= 200) ? 1u : 0u;
}

// ---------------- weight transpose: W[512][N] -> Wt[N][512] bf16, LDS tile ----------------
template <int N>
__global__ __launch_bounds__(256) void k_trans(const void* W, bf16* Wt, const u32t* flagp) {
    __shared__ float T[64][65];
    const int isbf = (int)flagp[0];
    const int n0 = blockIdx.x * 64, k0 = blockIdx.y * 64;
    const int t = threadIdx.x;
    const int lc = t & 63, lr = t >> 6;
#pragma unroll
    for (int rr = 0; rr < 16; ++rr) {
        int row = rr * 4 + lr;
        size_t g = (size_t)(k0 + row) * N + n0 + lc;
        float v = isbf ? (float)((const bf16*)W)[g] : ((const float*)W)[g];
        T[row][lc] = v;
    }
    __syncthreads();
#pragma unroll
    for (int rr = 0; rr < 16; ++rr) {
        int row = rr * 4 + lr;   // output row (n direction)
        Wt[(size_t)(n0 + row) * 512 + k0 + lc] = (bf16)T[lc][row];
    }
}

// ---------------- bias prep -> f32 ----------------
__global__ __launch_bounds__(256) void k_bias(const void* b_qkv, const void* b_proj,
                                              const u32t* flagp, char* ws) {
    float* bq = (float*)(ws + OFF_BQKV);
    float* bp = (float*)(ws + OFF_BPROJ);
    const int isbf = (int)flagp[0];
    int gid = blockIdx.x * 256 + threadIdx.x;
    if (gid < 1536)
        bq[gid] = isbf ? (float)((const bf16*)b_qkv)[gid] : ((const float*)b_qkv)[gid];
    else if (gid < 2048) {
        int o = gid - 1536;
        bp[o] = isbf ? (float)((const bf16*)b_proj)[o] : ((const float*)b_proj)[o];
    }
}

// ---------------- GEMM: C[M][NTOT] = A[M][512] * Bt[NTOT][512]^T + bias ----------------
// 128x128 tile, BK=64, 256 threads (4 waves each 64x64), XCD-swizzled flat grid.
// LDS tile = 128 rows x 8 col-chunks of 16B; physical chunk = (r<<3)|(c^(r&7)).
template <int NTOT>
__global__ __launch_bounds__(256) void k_gemm(const void* Ax, const bf16* Bt,
                                              const float* bias, void* Cp,
                                              const u32t* flagp, int amode, int omode) {
    __shared__ __align__(16) u16t As[8192];
    __shared__ __align__(16) u16t Bs[8192];
    constexpr int NBN = NTOT / 128;
    const int isbf = (int)flagp[0];
    const int a_is_f32 = (amode == 1) && !isbf;
    const int out_bf16 = (omode == 1) || isbf;

    const int t = threadIdx.x;
    const int w = t >> 6, lane = t & 63;
    const int ln = lane & 15, qd = lane >> 4;

    // XCD-aware swizzle: all NBN blocks of an m-group land on one XCD
    const int flat = blockIdx.x;
    const int xcd = flat & 7, slot = flat >> 3;
    const int n_idx = slot % NBN, grp = slot / NBN;
    const int m0 = (grp * 8 + xcd) * 128;
    const int n0 = n_idx * 128;
    const int wr = (w >> 1) * 64, wc = (w & 1) * 64;

    // staging: 4 chunks per thread per tile; inst q covers phys = w*256+q*64+lane
    u32t aoff[4], boff[4];
    int physl[4];
#pragma unroll
    for (int q = 0; q < 4; ++q) {
        int phys = w * 256 + q * 64 + lane;
        int r = phys >> 3, c = (phys & 7) ^ (r & 7);
        physl[q] = phys;
        aoff[q] = (u32t)(m0 + r) * 512 + c * 8;
        boff[q] = (u32t)(n0 + r) * 512 + c * 8;
    }
    // fragment LDS offsets for sub-k kk=0 (kk=1 = offset ^ 32)
    int aoffs[4], boffs[4];
#pragma unroll
    for (int i = 0; i < 4; ++i) {
        int ra = wr + i * 16 + ln;
        aoffs[i] = ((ra << 3) | (qd ^ (ra & 7))) * 8;
        int rb = wc + i * 16 + ln;
        boffs[i] = ((rb << 3) | (qd ^ (rb & 7))) * 8;
    }

    const bf16* Ab = (const bf16*)Ax;
    const float* Af = (const float*)Ax;

    f32x4 acc[4][4];
    f32x4 zero = {0.f, 0.f, 0.f, 0.f};
#pragma unroll
    for (int i = 0; i < 4; ++i)
#pragma unroll
        for (int j = 0; j < 4; ++j) acc[i][j] = zero;

    for (int kt = 0; kt < 8; ++kt) {
        if (a_is_f32) {
#pragma unroll
            for (int q = 0; q < 4; ++q) {
                float4 v0 = *(const float4*)(Af + aoff[q]);
                float4 v1 = *(const float4*)(Af + aoff[q] + 4);
                bf16x8 h;
                h[0] = (bf16)v0.x; h[1] = (bf16)v0.y; h[2] = (bf16)v0.z; h[3] = (bf16)v0.w;
                h[4] = (bf16)v1.x; h[5] = (bf16)v1.y; h[6] = (bf16)v1.z; h[7] = (bf16)v1.w;
                *(bf16x8*)(void*)&As[physl[q] * 8] = h;
            }
        } else {
#pragma unroll
            for (int q = 0; q < 4; ++q)
                GLL16(Ab + aoff[q], &As[(w * 256 + q * 64) * 8]);
        }
#pragma unroll
        for (int q = 0; q < 4; ++q)
            GLL16(Bt + boff[q], &Bs[(w * 256 + q * 64) * 8]);
        __syncthreads();
#pragma unroll
        for (int kk = 0; kk < 2; ++kk) {
            bf16x8 af[4], bfr[4];
#pragma unroll
            for (int i = 0; i < 4; ++i) af[i] = *(const bf16x8*)(void*)&As[aoffs[i] ^ (kk * 32)];
#pragma unroll
            for (int j = 0; j < 4; ++j) bfr[j] = *(const bf16x8*)(void*)&Bs[boffs[j] ^ (kk * 32)];
#pragma unroll
            for (int i = 0; i < 4; ++i)
#pragma unroll
                for (int j = 0; j < 4; ++j) acc[i][j] = MFMA16(af[i], bfr[j], acc[i][j]);
        }
        __syncthreads();
#pragma unroll
        for (int q = 0; q < 4; ++q) { aoff[q] += 64; boff[q] += 64; }
    }

    float bj[4];
#pragma unroll
    for (int j = 0; j < 4; ++j) bj[j] = bias[n0 + wc + j * 16 + ln];

    if (out_bf16) {
        bf16* C = (bf16*)Cp;
#pragma unroll
        for (int i = 0; i < 4; ++i)
#pragma unroll
            for (int j = 0; j < 4; ++j)
#pragma unroll
                for (int rr = 0; rr < 4; ++rr) {
                    size_t row = (size_t)m0 + wr + i * 16 + qd * 4 + rr;
                    int col = n0 + wc + j * 16 + ln;
                    C[row * NTOT + col] = (bf16)(acc[i][j][rr] + bj[j]);
                }
    } else {
        float* C = (float*)Cp;
#pragma unroll
        for (int i = 0; i < 4; ++i)
#pragma unroll
            for (int j = 0; j < 4; ++j)
#pragma unroll
                for (int rr = 0; rr < 4; ++rr) {
                    size_t row = (size_t)m0 + wr + i * 16 + qd * 4 + rr;
                    int col = n0 + wc + j * 16 + ln;
                    C[row * NTOT + col] = acc[i][j][rr] + bj[j];
                }
    }
}

// ---------------- fused gaussian-window attention: one wave per (b,h) ----------------
// XCD-swizzled so the 4 blocks of one batch index share an XCD (qkv tile L2 reuse).
__global__ __launch_bounds__(256) void k_attn(const bf16* qkv, bf16* attn) {
    __shared__ __align__(16) bf16 P[4][64 * 72];
    const int t = threadIdx.x;
    const int w = t >> 6, lane = t & 63;
    const int ln = lane & 15, qd = lane >> 4, q8 = qd * 8;
    const int flat = blockIdx.x;
    const int xcd = flat & 7, slot = flat >> 3;
    const int sub = slot & 3, grp = slot >> 2;
    const int b = grp * 8 + xcd;
    const int h = sub * 4 + w;
    const size_t rowbase = (size_t)b * 64 * 1536;
    const int colq = h * 32 + q8;

    bf16x8 aq[4], bk[4];
#pragma unroll
    for (int i = 0; i < 4; ++i)
        aq[i] = *(const bf16x8*)(qkv + rowbase + (size_t)(i * 16 + ln) * 1536 + colq);
#pragma unroll
    for (int j = 0; j < 4; ++j)
        bk[j] = *(const bf16x8*)(qkv + rowbase + (size_t)(j * 16 + ln) * 1536 + 512 + colq);

    f32x4 zero = {0.f, 0.f, 0.f, 0.f};
    f32x4 s[4][4];
#pragma unroll
    for (int i = 0; i < 4; ++i)
#pragma unroll
        for (int j = 0; j < 4; ++j) s[i][j] = MFMA16(aq[i], bk[j], zero);

    const float INV2S2 = 3.28731097961867f;   // 1/(2*0.39^2)
    {
        int c = lane & 7;
        float S1 = 0.f;
#pragma unroll
        for (int c2 = 0; c2 < 8; ++c2) {
            int d = c - c2;
            S1 += __expf(-(float)(d * d) * INV2S2);
        }
        float invS1 = 1.0f / S1;
        const int ymb = ln >> 3, xm = ln & 7, yq = qd >> 1, xq = (qd & 1) * 4;
        float FY[4][4], FX[4];
#pragma unroll
        for (int i = 0; i < 4; ++i) {
            int yn = 2 * i + yq;
            float g = __shfl(invS1, yn, 64);
#pragma unroll
            for (int j = 0; j < 4; ++j) {
                int dy = yn - (2 * j + ymb);
                FY[i][j] = __expf(-(float)(dy * dy) * INV2S2) * g;
            }
        }
#pragma unroll
        for (int rr = 0; rr < 4; ++rr) {
            int xn = xq + rr;
            int dx = xn - xm;
            FX[rr] = __expf(-(float)(dx * dx) * INV2S2) * __shfl(invS1, xn, 64);
        }

        const float SCALE = 0.17677669529663687f;  // 1/sqrt(32)
#pragma unroll
        for (int i = 0; i < 4; ++i)
#pragma unroll
            for (int rr = 0; rr < 4; ++rr) {
                float lj[4];
                float mx = -1e30f;
#pragma unroll
                for (int j = 0; j < 4; ++j) {
                    lj[j] = s[i][j][rr] * SCALE * FY[i][j] * FX[rr];
                    mx = fmaxf(mx, lj[j]);
                }
                mx = fmaxf(mx, __shfl_xor(mx, 1));
                mx = fmaxf(mx, __shfl_xor(mx, 2));
                mx = fmaxf(mx, __shfl_xor(mx, 4));
                mx = fmaxf(mx, __shfl_xor(mx, 8));
                float sum = 0.f;
#pragma unroll
                for (int j = 0; j < 4; ++j) {
                    lj[j] = __expf(lj[j] - mx);
                    sum += lj[j];
                }
                sum += __shfl_xor(sum, 1);
                sum += __shfl_xor(sum, 2);
                sum += __shfl_xor(sum, 4);
                sum += __shfl_xor(sum, 8);
                float inv = 1.0f / sum;
                int n = i * 16 + qd * 4 + rr;
#pragma unroll
                for (int j = 0; j < 4; ++j)
                    P[w][n * 72 + j * 16 + ln] = (bf16)(lj[j] * inv);
            }
    }

    f32x4 o[4][2];
#pragma unroll
    for (int i = 0; i < 4; ++i) {
        o[i][0] = zero;
        o[i][1] = zero;
    }
#pragma unroll
    for (int kc = 0; kc < 64; kc += 32) {
        bf16x8 bv[2];
#pragma unroll
        for (int j2 = 0; j2 < 2; ++j2)
#pragma unroll
            for (int jj = 0; jj < 8; ++jj)
                bv[j2][jj] = qkv[rowbase + (size_t)(kc + q8 + jj) * 1536 + 1024 + h * 32 + j2 * 16 + ln];
#pragma unroll
        for (int i = 0; i < 4; ++i) {
            bf16x8 ap = *(const bf16x8*)(void*)&P[w][(i * 16 + ln) * 72 + kc + q8];
#pragma unroll
            for (int j2 = 0; j2 < 2; ++j2) o[i][j2] = MFMA16(ap, bv[j2], o[i][j2]);
        }
    }
#pragma unroll
    for (int i = 0; i < 4; ++i)
#pragma unroll
        for (int j2 = 0; j2 < 2; ++j2)
#pragma unroll
            for (int rr = 0; rr < 4; ++rr)
                attn[((size_t)b * 64 + i * 16 + qd * 4 + rr) * 512 + h * 32 + j2 * 16 + ln] =
                    (bf16)(o[i][j2][rr]);
}

extern "C" void kernel_launch(void* const* d_in, const int* in_sizes, int n_in,
                              void* d_out, int out_size, void* d_ws, size_t ws_size,
                              hipStream_t stream) {
    const void* x = d_in[0];
    const void* w_qkv = d_in[1];
    const void* b_qkv = d_in[2];
    const void* w_proj = d_in[3];
    const void* b_proj = d_in[4];
    char* ws = (char*)d_ws;
    u32t* flag = (u32t*)(ws + OFF_FLAG);
    bf16* wqkvT = (bf16*)(ws + OFF_WQKVT);
    bf16* wprojT = (bf16*)(ws + OFF_WPROJT);
    float* bq = (float*)(ws + OFF_BQKV);
    float* bp = (float*)(ws + OFF_BPROJ);
    bf16* qkv = (bf16*)(ws + OFF_QKV);
    bf16* attn = (bf16*)(ws + OFF_ATTN);

    k_detect<<<1, 256, 0, stream>>>((const u16t*)x, flag);
    k_trans<1536><<<dim3(24, 8), 256, 0, stream>>>(w_qkv, wqkvT, flag);
    k_trans<512><<<dim3(8, 8), 256, 0, stream>>>(w_proj, wprojT, flag);
    k_bias<<<8, 256, 0, stream>>>(b_qkv, b_proj, flag, ws);
    // QKV GEMM: [131072,512] @ [512,1536] -> qkv bf16 (12*1024 = 12288 blocks)
    k_gemm<1536><<<12288, 256, 0, stream>>>(x, wqkvT, bq, qkv, flag, 1, 1);
    // attention
    k_attn<<<8192, 256, 0, stream>>>(qkv, attn);
    // proj GEMM: [131072,512] @ [512,512] -> d_out (4*1024 = 4096 blocks)
    k_gemm<512><<<4096, 256, 0, stream>>>(attn, wprojT, bp, d_out, flag, 0, 2);
}